// Round 2
// baseline (955.251 us; speedup 1.0000x reference)
//
#include <hip/hip_runtime.h>

// QuatE scoring, MI355X. fp32 via bf16 hi/lo split (3 MFMA products).
// R2: 256x256 tile, 8 waves, BK=32, 128KB dbuf LDS, 4-phase schedule,
// fragment-ordered weight images + pre-swizzled-source A staging via global_load_lds.

using bf16x8 = __attribute__((ext_vector_type(8))) short;
using f32x4  = __attribute__((ext_vector_type(4))) float;

#define DEVINL static __device__ __forceinline__

// split two fp32 into packed bf16 hi pair + lo pair (truncation split)
DEVINL void split2(float x0, float x1, unsigned& h, unsigned& l) {
  unsigned u0 = __float_as_uint(x0), u1 = __float_as_uint(x1);
  unsigned h0 = u0 & 0xFFFF0000u, h1 = u1 & 0xFFFF0000u;
  h = (u0 >> 16) | h1;
  float r0 = x0 - __uint_as_float(h0);
  float r1 = x1 - __uint_as_float(h1);
  l = (__float_as_uint(r0) >> 16) | (__float_as_uint(r1) & 0xFFFF0000u);
}

DEVINL bf16x8 pack4(unsigned a, unsigned b, unsigned c, unsigned d) {
  union { unsigned u[4]; bf16x8 v; } t;
  t.u[0] = a; t.u[1] = b; t.u[2] = c; t.u[3] = d;
  return t.v;
}

// async global->LDS, 16B per lane; lds dest = uniform base + lane*16
DEVINL void gload16(const void* g, void* l) {
  __builtin_amdgcn_global_load_lds(
      (const __attribute__((address_space(1))) unsigned*)g,
      (__attribute__((address_space(3))) unsigned*)l, 16, 0, 0);
}

// ---------------- weight conversion: W fp32 [256][srcK] -> fragment-ordered images
// per K-tile (32 cols): [hi 16KB][lo 16KB]; chunk layout: n16-group (row>>4) * 1KB,
// within group chunk = (row&15) + kc8*16 (matches 16x16x32 B-frag lane order).
__global__ void convert_b(const float* __restrict__ src, int srcK,
                          char* __restrict__ dst)
{
  const int tile = blockIdx.x;
  const int wrow = threadIdx.x;            // 0..255
  char* base = dst + (size_t)tile * 32768;
  const float* srow = src + (size_t)wrow * srcK;
#pragma unroll
  for (int kc8 = 0; kc8 < 4; ++kc8) {
    int k0 = tile * 32 + kc8 * 8;
    float x[8];
    if (k0 + 8 <= srcK) {
      float4 v0 = *(const float4*)(srow + k0);
      float4 v1 = *(const float4*)(srow + k0 + 4);
      x[0] = v0.x; x[1] = v0.y; x[2] = v0.z; x[3] = v0.w;
      x[4] = v1.x; x[5] = v1.y; x[6] = v1.z; x[7] = v1.w;
    } else {
#pragma unroll
      for (int j = 0; j < 8; ++j) x[j] = (k0 + j < srcK) ? srow[k0 + j] : 0.f;
    }
    unsigned hh[4], ll[4];
    split2(x[0], x[1], hh[0], ll[0]);
    split2(x[2], x[3], hh[1], ll[1]);
    split2(x[4], x[5], hh[2], ll[2]);
    split2(x[6], x[7], hh[3], ll[3]);
    int lchunk = (wrow & 15) + kc8 * 16;
    int n16 = wrow >> 4;
    *(uint4*)(base + (size_t)n16 * 1024 + lchunk * 16)        = make_uint4(hh[0], hh[1], hh[2], hh[3]);
    *(uint4*)(base + 16384 + (size_t)n16 * 1024 + lchunk * 16) = make_uint4(ll[0], ll[1], ll[2], ll[3]);
  }
}

// ---------------- r padding: fp32 [2048][500] -> fp32 [2048][512] zero-padded
__global__ void pad_r(const float* __restrict__ src, float* __restrict__ dst)
{
  int row = blockIdx.y;
  int c4 = threadIdx.x;                    // 0..127
  int k = c4 * 4;
  float4 v = make_float4(0.f, 0.f, 0.f, 0.f);
  if (k + 3 < 500) v = *(const float4*)(src + (size_t)row * 500 + k);
  *(float4*)(dst + (size_t)row * 512 + k) = v;
}

// ---------------- 3-product split GEMM, 256x256 tile, 8 waves, BK=32 ----------------
// C[ks][M][N] = A_hi*B_hi + A_lo*B_hi + A_hi*B_lo  (A fp32 staged+split, B from images)
// LDS per buf (64KB): [A fp32 32KB: 16 groups x 2KB, chunk (r15*8 + (kc4^(r15&7)))]
//                     [B hi 16KB][B lo 16KB: n16*1KB + lane*16]
__global__ __launch_bounds__(512, 2) void gemm3p(
    const float* __restrict__ A0, const float* __restrict__ A1, int mtA0, long lda,
    const unsigned short* __restrict__ Bimg, int ktilesTot,
    float* __restrict__ C, long ldc, int MT, int NT, int KS, int swz)
{
  extern __shared__ char smem[];
  const int tid = threadIdx.x;
  const int bid = blockIdx.x;

  int mt, nt, ks;
  if (swz) {  // grid == 256: xcd-contiguous mapping (bijective)
    int x = bid & 7, i = bid >> 3;
    nt = x & 3; mt = (x >> 2) * 8 + (i & 7); ks = i >> 3;
  } else {
    nt = bid % NT; int q = bid / NT; mt = q % MT; ks = q / MT;
  }

  const int kt0 = (ktilesTot * ks) / KS;
  const int kt1 = (ktilesTot * (ks + 1)) / KS;

  const float* Ablk = (mt < mtA0) ? (A0 + (size_t)mt * 256 * lda)
                                  : (A1 + (size_t)(mt - mtA0) * 256 * lda);
  const char* BimgT = (const char*)Bimg + (size_t)nt * ktilesTot * 32768;

  const int wid = tid >> 6, lane = tid & 63;
  const int wr = wid >> 2, wc = wid & 3;
  const int l15 = lane & 15, lq = lane >> 4;

  // A stage per-lane source pointers (pre-swizzled so LDS image = swizzled tile)
  const char* aptr[4];
#pragma unroll
  for (int i = 0; i < 4; ++i) {
    int c = (i & 1) * 64 + lane;
    int r15 = c >> 3;
    int kc4 = (c & 7) ^ (r15 & 7);
    int row = (2 * wid + (i >> 1)) * 16 + r15;
    aptr[i] = (const char*)(Ablk + (size_t)row * lda) + (size_t)kt0 * 128 + kc4 * 16;
  }
  const char* bptr = BimgT + (size_t)kt0 * 32768 + (size_t)wid * 4096 + lane * 16;

  // A fragment read offsets (within 2KB group): two 16B chunks per fragment
  int aoffs[2];
#pragma unroll
  for (int s = 0; s < 2; ++s)
    aoffs[s] = (l15 * 8 + ((lq * 2 + s) ^ (l15 & 7))) * 16;
  const int boff = lane * 16;

  f32x4 acc[8][4];
#pragma unroll
  for (int i = 0; i < 8; ++i)
#pragma unroll
    for (int j = 0; j < 4; ++j)
#pragma unroll
      for (int e = 0; e < 4; ++e) acc[i][j][e] = 0.f;

  // prologue: stage kt0 into buf0
  {
    char* nb = smem;
#pragma unroll
    for (int i = 0; i < 4; ++i) {
      gload16(aptr[i], nb + (size_t)wid * 4096 + i * 1024);
      aptr[i] += 128;
    }
#pragma unroll
    for (int i = 0; i < 4; ++i)
      gload16(bptr + i * 1024, nb + 32768 + (size_t)wid * 4096 + i * 1024);
    bptr += 32768;
  }
  asm volatile("s_waitcnt vmcnt(0)" ::: "memory");
  __builtin_amdgcn_s_barrier();

  for (int kt = kt0; kt < kt1; ++kt) {
    char* bufc = smem + (size_t)((kt - kt0) & 1) * 65536;
    char* bufn = smem + (size_t)(((kt - kt0) & 1) ^ 1) * 65536;
    const bool nx = (kt + 1 < kt1);
#pragma unroll
    for (int p = 0; p < 4; ++p) {
      const int qm = p & 1, qn = p >> 1;

      // stage next K-tile early (A at p0, B at p1) -- stays in flight across barriers
      if (p == 0 && nx) {
#pragma unroll
        for (int i = 0; i < 4; ++i) {
          gload16(aptr[i], bufn + (size_t)wid * 4096 + i * 1024);
          aptr[i] += 128;
        }
      }
      if (p == 1 && nx) {
#pragma unroll
        for (int i = 0; i < 4; ++i)
          gload16(bptr + i * 1024, bufn + 32768 + (size_t)wid * 4096 + i * 1024);
        bptr += 32768;
      }

      // fragment loads + in-register split (pre-barrier)
      bf16x8 bh[2], bl[2];
#pragma unroll
      for (int j = 0; j < 2; ++j) {
        int n16 = wc * 4 + qn * 2 + j;
        bh[j] = *(const bf16x8*)(bufc + 32768 + (size_t)n16 * 1024 + boff);
        bl[j] = *(const bf16x8*)(bufc + 49152 + (size_t)n16 * 1024 + boff);
      }
      bf16x8 ah[4], al[4];
#pragma unroll
      for (int i2 = 0; i2 < 4; ++i2) {
        int gm = wr * 8 + qm * 4 + i2;
        const char* ab = bufc + (size_t)gm * 2048;
        float4 a0 = *(const float4*)(ab + aoffs[0]);
        float4 a1 = *(const float4*)(ab + aoffs[1]);
        unsigned hh[4], ll[4];
        split2(a0.x, a0.y, hh[0], ll[0]);
        split2(a0.z, a0.w, hh[1], ll[1]);
        split2(a1.x, a1.y, hh[2], ll[2]);
        split2(a1.z, a1.w, hh[3], ll[3]);
        ah[i2] = pack4(hh[0], hh[1], hh[2], hh[3]);
        al[i2] = pack4(ll[0], ll[1], ll[2], ll[3]);
      }

      __builtin_amdgcn_s_barrier();
      __builtin_amdgcn_sched_barrier(0);
      __builtin_amdgcn_s_setprio(1);
#pragma unroll
      for (int j = 0; j < 2; ++j)
#pragma unroll
        for (int i2 = 0; i2 < 4; ++i2) {
          f32x4* a = &acc[qm * 4 + i2][qn * 2 + j];
          *a = __builtin_amdgcn_mfma_f32_16x16x32_bf16(ah[i2], bh[j], *a, 0, 0, 0);
          *a = __builtin_amdgcn_mfma_f32_16x16x32_bf16(al[i2], bh[j], *a, 0, 0, 0);
          *a = __builtin_amdgcn_mfma_f32_16x16x32_bf16(ah[i2], bl[j], *a, 0, 0, 0);
        }
      __builtin_amdgcn_s_setprio(0);
      if (p == 3) asm volatile("s_waitcnt vmcnt(0)" ::: "memory");
      __builtin_amdgcn_s_barrier();
    }
  }

  // C write. 16x16x32 D layout: col = lane&15, row = (lane>>4)*4 + reg
  float* Cb = C + (size_t)ks * (size_t)(MT * 256) * (size_t)ldc;
  const long rowbase = (long)mt * 256 + wr * 128 + lq * 4;
  const long colbase = (long)nt * 256 + wc * 64 + l15;
#pragma unroll
  for (int i = 0; i < 8; ++i)
#pragma unroll
    for (int j = 0; j < 4; ++j)
#pragma unroll
      for (int reg = 0; reg < 4; ++reg) {
        long row = rowbase + i * 16 + reg;
        long col = colbase + j * 16;
        Cb[(size_t)row * ldc + col] = acc[i][j][reg];
      }
}

// ---------------- epilogue: k-split sum, norm, Hamilton, row dot, sigmoid ----------------
__global__ void epilogue_kernel(const float* __restrict__ C1, const float* __restrict__ C2,
                                float* __restrict__ out, int KS)
{
  const int b = blockIdx.x;        // 0..2047
  const int d = threadIdx.x;       // 0..255
  const size_t SZ = 4096ull * 1024ull;

  float Hq[4], Tq[4], Rq[4];
#pragma unroll
  for (int q = 0; q < 4; ++q) {
    float hv = 0.f, tv = 0.f;
    for (int ks = 0; ks < KS; ++ks) {
      hv += C1[ks * SZ + (size_t)b * 1024 + q * 256 + d];
      tv += C1[ks * SZ + (size_t)(b + 2048) * 1024 + q * 256 + d];
    }
    Hq[q] = hv; Tq[q] = tv;
    Rq[q] = C2[(size_t)b * 1024 + q * 256 + d];
  }
  float nn = Rq[0]*Rq[0] + Rq[1]*Rq[1] + Rq[2]*Rq[2] + Rq[3]*Rq[3];
  float Qr = Hq[0]*Rq[0] - Hq[1]*Rq[1] - Hq[2]*Rq[2] - Hq[3]*Rq[3];
  float Qi = Hq[0]*Rq[1] + Hq[1]*Rq[0] + Hq[2]*Rq[3] - Hq[3]*Rq[2];
  float Qj = Hq[0]*Rq[2] - Hq[1]*Rq[3] + Hq[2]*Rq[0] + Hq[3]*Rq[1];
  float Qk = Hq[0]*Rq[3] + Hq[1]*Rq[2] - Hq[2]*Rq[1] + Hq[3]*Rq[0];
  float ss = Qr*Tq[0] + Qi*Tq[1] + Qj*Tq[2] + Qk*Tq[3];

#pragma unroll
  for (int o = 32; o; o >>= 1) {
    ss += __shfl_xor(ss, o);
    nn += __shfl_xor(nn, o);
  }
  __shared__ float red[8];
  int lane = d & 63, w = d >> 6;
  if (lane == 0) { red[w] = ss; red[4 + w] = nn; }
  __syncthreads();
  if (d == 0) {
    float S = red[0] + red[1] + red[2] + red[3];
    float N = red[4] + red[5] + red[6] + red[7];
    float score = sqrtf(N) * S;       // score is linear in R -> scale once by norm
    out[b] = 1.f / (1.f + expf(-score));
  }
}

// ---------------- launch ----------------
extern "C" void kernel_launch(void* const* d_in, const int* in_sizes, int n_in,
                              void* d_out, int out_size, void* d_ws, size_t ws_size,
                              hipStream_t stream)
{
  const float* h = (const float*)d_in[0];
  const float* t = (const float*)d_in[1];
  const float* r = (const float*)d_in[2];
  const float* We[4] = {(const float*)d_in[3], (const float*)d_in[4],
                        (const float*)d_in[5], (const float*)d_in[6]};
  const float* Wr[4] = {(const float*)d_in[7], (const float*)d_in[8],
                        (const float*)d_in[9], (const float*)d_in[10]};
  float* out = (float*)d_out;

  char* ws = (char*)d_ws;
  const size_t offB  = 0;                         // entity B images: 4*625*32768 = 81,920,000
  const size_t offWr = 81920000;                  // Wr images: 4*16*32768 = 2,097,152
  const size_t offR  = offWr + 2097152;           // rpad: 2048*512*4 = 4,194,304
  const size_t offC1 = offR + 4194304;            // 88,211,456
  const size_t C1sz  = 4096ull * 1024ull * 4ull;  // 16,777,216 per ks
  const int KS = (ws_size >= offC1 + 4 * C1sz + 8388608ull) ? 4 : 2;
  const size_t offC2 = offC1 + (size_t)KS * C1sz;

  float* rpad = (float*)(ws + offR);
  float* C1   = (float*)(ws + offC1);
  float* C2   = (float*)(ws + offC2);

  for (int q = 0; q < 4; ++q) {
    convert_b<<<dim3(625), 256, 0, stream>>>(We[q], 20000, ws + offB + (size_t)q * 625 * 32768);
    convert_b<<<dim3(16), 256, 0, stream>>>(Wr[q], 500, ws + offWr + (size_t)q * 16 * 32768);
  }
  pad_r<<<dim3(1, 2048), 128, 0, stream>>>(r, rpad);

  // main: M=4096 ([h;t]), N=1024, K=20000 (625 K-tiles); MT=16 NT=4
  gemm3p<<<dim3(16 * 4 * KS), 512, 131072, stream>>>(
      h, t, 8, 20000L, (const unsigned short*)(ws + offB), 625,
      C1, 1024L, 16, 4, KS, KS == 4 ? 1 : 0);
  // r: M=2048, N=1024, K=512 (16 K-tiles); MT=8 NT=4 KS=1
  gemm3p<<<dim3(32), 512, 131072, stream>>>(
      rpad, rpad, 8, 512L, (const unsigned short*)(ws + offWr), 16,
      C2, 1024L, 8, 4, 1, 0);

  epilogue_kernel<<<dim3(2048), 256, 0, stream>>>(C1, C2, out, KS);
}

// Round 3
// 687.177 us; speedup vs baseline: 1.3901x; 1.3901x over previous
//
#include <hip/hip_runtime.h>

// QuatE scoring, MI355X. fp32 via bf16 hi/lo split (3 MFMA products).
// R3: 256x256 tile, 8 waves, BK=32, 128KB dbuf LDS, ONE barrier per K-tile.
// A: global->reg->split(once)->ds_write into XOR-swizzled fragment layout.
// B: pre-converted fragment-ordered images staged via global_load_lds (linear).
// Fragments read once per K-tile; mid-iteration A-split overlaps MFMA stream.

using bf16x8 = __attribute__((ext_vector_type(8))) short;
using f32x4  = __attribute__((ext_vector_type(4))) float;

#define DEVINL static __device__ __forceinline__

// split two fp32 into packed bf16 hi pair + lo pair (truncation split)
DEVINL void split2(float x0, float x1, unsigned& h, unsigned& l) {
  unsigned u0 = __float_as_uint(x0), u1 = __float_as_uint(x1);
  unsigned h0 = u0 & 0xFFFF0000u, h1 = u1 & 0xFFFF0000u;
  h = (u0 >> 16) | h1;
  float r0 = x0 - __uint_as_float(h0);
  float r1 = x1 - __uint_as_float(h1);
  l = (__float_as_uint(r0) >> 16) | (__float_as_uint(r1) & 0xFFFF0000u);
}

// async global->LDS, 16B per lane; lds dest = uniform base + lane*16
DEVINL void gload16(const void* g, void* l) {
  __builtin_amdgcn_global_load_lds(
      (const __attribute__((address_space(1))) unsigned*)g,
      (__attribute__((address_space(3))) unsigned*)l, 16, 0, 0);
}

// ---------------- weight conversion: W fp32 [256][srcK] -> fragment-ordered images
// per K-tile (32 cols): [hi 16KB][lo 16KB]; chunk = (n&15) + kgrp*16 within n16-group.
__global__ void convert_b(const float* __restrict__ src, int srcK,
                          char* __restrict__ dst)
{
  const int tile = blockIdx.x;
  const int wrow = threadIdx.x;            // 0..255 (= output col n)
  char* base = dst + (size_t)tile * 32768;
  const float* srow = src + (size_t)wrow * srcK;
#pragma unroll
  for (int kc8 = 0; kc8 < 4; ++kc8) {
    int k0 = tile * 32 + kc8 * 8;
    float x[8];
    if (k0 + 8 <= srcK) {
      float4 v0 = *(const float4*)(srow + k0);
      float4 v1 = *(const float4*)(srow + k0 + 4);
      x[0] = v0.x; x[1] = v0.y; x[2] = v0.z; x[3] = v0.w;
      x[4] = v1.x; x[5] = v1.y; x[6] = v1.z; x[7] = v1.w;
    } else {
#pragma unroll
      for (int j = 0; j < 8; ++j) x[j] = (k0 + j < srcK) ? srow[k0 + j] : 0.f;
    }
    unsigned hh[4], ll[4];
    split2(x[0], x[1], hh[0], ll[0]);
    split2(x[2], x[3], hh[1], ll[1]);
    split2(x[4], x[5], hh[2], ll[2]);
    split2(x[6], x[7], hh[3], ll[3]);
    int lchunk = (wrow & 15) + kc8 * 16;
    int n16 = wrow >> 4;
    *(uint4*)(base + (size_t)n16 * 1024 + lchunk * 16)         = make_uint4(hh[0], hh[1], hh[2], hh[3]);
    *(uint4*)(base + 16384 + (size_t)n16 * 1024 + lchunk * 16) = make_uint4(ll[0], ll[1], ll[2], ll[3]);
  }
}

// ---------------- r padding: fp32 [2048][500] -> fp32 [2048][512] zero-padded
__global__ void pad_r(const float* __restrict__ src, float* __restrict__ dst)
{
  int row = blockIdx.y;
  int c4 = threadIdx.x;                    // 0..127
  int k = c4 * 4;
  float4 v = make_float4(0.f, 0.f, 0.f, 0.f);
  if (k + 3 < 500) v = *(const float4*)(src + (size_t)row * 500 + k);
  *(float4*)(dst + (size_t)row * 512 + k) = v;
}

// ---------------- 3-product split GEMM ----------------
// LDS per 64KB buf: A region 32KB = 16 m16-groups x (hi 1KB + lo 1KB),
//   chunk addr = ((m15 ^ kg) + kg*16)*16  (XOR keeps ds_write_b64 conflict-free);
// B region 32KB at +32768 = image-mirrored linear [n16][chunk][16B], hi then lo.
__global__ __launch_bounds__(512, 2) void gemm3p(
    const float* __restrict__ A0, const float* __restrict__ A1, int mtA0, long lda,
    const char* __restrict__ Bimg, int ktilesTot,
    float* __restrict__ C, long ldc, int MT, int NT, int KS, int swz)
{
  extern __shared__ char smem[];
  const int tid = threadIdx.x;
  const int bid = blockIdx.x;

  int mt, nt, ks;
  if (swz) {  // grid 256: same (mt,ks) quad of nt -> same XCD (bid%8 equal)
    int x = bid & 7, w = bid >> 3;
    nt = w & 3;
    int g = x + (w >> 2) * 8;
    mt = g & 15; ks = g >> 4;
  } else {
    nt = bid % NT; int q = bid / NT; mt = q % MT; ks = q / MT;
  }

  const int kt0 = (ktilesTot * ks) / KS;
  const int kt1 = (ktilesTot * (ks + 1)) / KS;

  const float* Ablk = (mt < mtA0) ? (A0 + (size_t)mt * 256 * lda)
                                  : (A1 + (size_t)(mt - mtA0) * 256 * lda);
  const char* Bt = Bimg + ((size_t)nt * ktilesTot + kt0) * 32768;

  const int wid = tid >> 6, lane = tid & 63;
  const int wr = wid >> 2, wc = wid & 3;
  const int l15 = lane & 15, lq = lane >> 4;

  // A global source: row = wid*32 + 8i + (lane>>3), fp32 col = 4*(lane&7)
  const float* aSrc = Ablk + (size_t)(wid * 32 + (lane >> 3)) * lda
                      + (size_t)kt0 * 32 + 4 * (lane & 7);

  // A ds_write offsets (4 loads -> hi uint2 at awoff, lo at +1024)
  int awoff[4];
  {
    int kg = (lane & 7) >> 1, half = lane & 1;
#pragma unroll
    for (int i = 0; i < 4; ++i) {
      int m15 = (lane >> 3) + 8 * (i & 1);
      awoff[i] = (2 * wid + (i >> 1)) * 2048 + (((m15 ^ kg) + kg * 16) << 4) + half * 8;
    }
  }
  // A fragment read offset within an m16-group (lane&15 = m, lane>>4 = k-octet)
  const int aroff = (((l15 ^ lq) + lq * 16) << 4);
  // B fragment base: n16 group (wc*4 + j), chunk = lane (linear, conflict-free)
  const int bbase = 32768 + (wc * 4) * 1024 + lane * 16;

  f32x4 acc[8][4];
#pragma unroll
  for (int m = 0; m < 8; ++m)
#pragma unroll
    for (int j = 0; j < 4; ++j)
#pragma unroll
      for (int e = 0; e < 4; ++e) acc[m][j][e] = 0.f;

  float4 aR[4];

#define ISSUE_A(KT)                                                            \
  {                                                                            \
    const float* p_ = aSrc + (size_t)((KT) - kt0) * 32;                        \
    _Pragma("unroll")                                                          \
    for (int i = 0; i < 4; ++i) aR[i] = *(const float4*)(p_ + (size_t)(8 * i) * lda); \
  }
#define ISSUE_B(DST, KT)                                                       \
  {                                                                            \
    const char* p_ = Bt + (size_t)((KT) - kt0) * 32768 + wid * 4096 + lane * 16; \
    _Pragma("unroll")                                                          \
    for (int i = 0; i < 4; ++i)                                                \
      gload16(p_ + i * 1024, (DST) + 32768 + wid * 4096 + i * 1024);           \
  }
#define WRITE_A(DST)                                                           \
  {                                                                            \
    _Pragma("unroll")                                                          \
    for (int i = 0; i < 4; ++i) {                                              \
      unsigned h0_, l0_, h1_, l1_;                                             \
      split2(aR[i].x, aR[i].y, h0_, l0_);                                      \
      split2(aR[i].z, aR[i].w, h1_, l1_);                                      \
      *(uint2*)((DST) + awoff[i])        = make_uint2(h0_, h1_);               \
      *(uint2*)((DST) + awoff[i] + 1024) = make_uint2(l0_, l1_);               \
    }                                                                          \
  }

  // prologue: stage kt0 into buf0
  ISSUE_A(kt0);
  ISSUE_B(smem, kt0);
  WRITE_A(smem);  // compiler waits the aR loads via dataflow
  asm volatile("s_waitcnt vmcnt(0)" ::: "memory");
  asm volatile("s_waitcnt lgkmcnt(0)" ::: "memory");
  __builtin_amdgcn_s_barrier();

  for (int kt = kt0; kt < kt1; ++kt) {
    char* bufc = smem + (size_t)((kt - kt0) & 1) * 65536;
    char* bufn = smem + (size_t)(((kt - kt0) & 1) ^ 1) * 65536;
    const bool nx = (kt + 1 < kt1);

    if (nx) { ISSUE_A(kt + 1); ISSUE_B(bufn, kt + 1); }

    // B fragments: read once, held across the K-tile
    bf16x8 bh[4], bl[4];
#pragma unroll
    for (int j = 0; j < 4; ++j) {
      bh[j] = *(const bf16x8*)(bufc + bbase + j * 1024);
      bl[j] = *(const bf16x8*)(bufc + bbase + j * 1024 + 16384);
    }

    __builtin_amdgcn_s_setprio(1);
#pragma unroll
    for (int m = 0; m < 4; ++m) {
      const char* ab = bufc + (wr * 8 + m) * 2048;
      bf16x8 ah = *(const bf16x8*)(ab + aroff);
      bf16x8 al = *(const bf16x8*)(ab + aroff + 1024);
#pragma unroll
      for (int j = 0; j < 4; ++j) {
        acc[m][j] = __builtin_amdgcn_mfma_f32_16x16x32_bf16(ah, bh[j], acc[m][j], 0, 0, 0);
        acc[m][j] = __builtin_amdgcn_mfma_f32_16x16x32_bf16(al, bh[j], acc[m][j], 0, 0, 0);
        acc[m][j] = __builtin_amdgcn_mfma_f32_16x16x32_bf16(ah, bl[j], acc[m][j], 0, 0, 0);
      }
    }
    __builtin_amdgcn_s_setprio(0);

    // mid-iteration: split+write A(t+1); pinned below first half, interleaves with second
    __builtin_amdgcn_sched_barrier(0);
    if (nx) WRITE_A(bufn);

    __builtin_amdgcn_s_setprio(1);
#pragma unroll
    for (int m = 4; m < 8; ++m) {
      const char* ab = bufc + (wr * 8 + m) * 2048;
      bf16x8 ah = *(const bf16x8*)(ab + aroff);
      bf16x8 al = *(const bf16x8*)(ab + aroff + 1024);
#pragma unroll
      for (int j = 0; j < 4; ++j) {
        acc[m][j] = __builtin_amdgcn_mfma_f32_16x16x32_bf16(ah, bh[j], acc[m][j], 0, 0, 0);
        acc[m][j] = __builtin_amdgcn_mfma_f32_16x16x32_bf16(al, bh[j], acc[m][j], 0, 0, 0);
        acc[m][j] = __builtin_amdgcn_mfma_f32_16x16x32_bf16(ah, bl[j], acc[m][j], 0, 0, 0);
      }
    }
    __builtin_amdgcn_s_setprio(0);

    // drain B gloads (issued a full K-tile ago -> ~free) + LDS, then sync
    asm volatile("s_waitcnt vmcnt(0)" ::: "memory");
    asm volatile("s_waitcnt lgkmcnt(0)" ::: "memory");
    __builtin_amdgcn_s_barrier();
  }
#undef ISSUE_A
#undef ISSUE_B
#undef WRITE_A

  // C write. 16x16x32 D layout: col = lane&15, row = (lane>>4)*4 + reg
  float* Cb = C + (size_t)ks * (size_t)(MT * 256) * (size_t)ldc;
  const long rowbase = (long)mt * 256 + wr * 128 + lq * 4;
  const long colbase = (long)nt * 256 + wc * 64 + l15;
#pragma unroll
  for (int m = 0; m < 8; ++m)
#pragma unroll
    for (int j = 0; j < 4; ++j)
#pragma unroll
      for (int reg = 0; reg < 4; ++reg) {
        long row = rowbase + m * 16 + reg;
        long col = colbase + j * 16;
        Cb[(size_t)row * ldc + col] = acc[m][j][reg];
      }
}

// ---------------- epilogue: k-split sum, norm, Hamilton, row dot, sigmoid ----------------
__global__ void epilogue_kernel(const float* __restrict__ C1, const float* __restrict__ C2,
                                float* __restrict__ out, int KS)
{
  const int b = blockIdx.x;        // 0..2047
  const int d = threadIdx.x;       // 0..255
  const size_t SZ = 4096ull * 1024ull;

  float Hq[4], Tq[4], Rq[4];
#pragma unroll
  for (int q = 0; q < 4; ++q) {
    float hv = 0.f, tv = 0.f;
    for (int ks = 0; ks < KS; ++ks) {
      hv += C1[ks * SZ + (size_t)b * 1024 + q * 256 + d];
      tv += C1[ks * SZ + (size_t)(b + 2048) * 1024 + q * 256 + d];
    }
    Hq[q] = hv; Tq[q] = tv;
    Rq[q] = C2[(size_t)b * 1024 + q * 256 + d];
  }
  float nn = Rq[0]*Rq[0] + Rq[1]*Rq[1] + Rq[2]*Rq[2] + Rq[3]*Rq[3];
  float Qr = Hq[0]*Rq[0] - Hq[1]*Rq[1] - Hq[2]*Rq[2] - Hq[3]*Rq[3];
  float Qi = Hq[0]*Rq[1] + Hq[1]*Rq[0] + Hq[2]*Rq[3] - Hq[3]*Rq[2];
  float Qj = Hq[0]*Rq[2] - Hq[1]*Rq[3] + Hq[2]*Rq[0] + Hq[3]*Rq[1];
  float Qk = Hq[0]*Rq[3] + Hq[1]*Rq[2] - Hq[2]*Rq[1] + Hq[3]*Rq[0];
  float ss = Qr*Tq[0] + Qi*Tq[1] + Qj*Tq[2] + Qk*Tq[3];

#pragma unroll
  for (int o = 32; o; o >>= 1) {
    ss += __shfl_xor(ss, o);
    nn += __shfl_xor(nn, o);
  }
  __shared__ float red[8];
  int lane = d & 63, w = d >> 6;
  if (lane == 0) { red[w] = ss; red[4 + w] = nn; }
  __syncthreads();
  if (d == 0) {
    float S = red[0] + red[1] + red[2] + red[3];
    float N = red[4] + red[5] + red[6] + red[7];
    float score = sqrtf(N) * S;       // score is linear in R -> scale once by norm
    out[b] = 1.f / (1.f + expf(-score));
  }
}

// ---------------- launch ----------------
extern "C" void kernel_launch(void* const* d_in, const int* in_sizes, int n_in,
                              void* d_out, int out_size, void* d_ws, size_t ws_size,
                              hipStream_t stream)
{
  const float* h = (const float*)d_in[0];
  const float* t = (const float*)d_in[1];
  const float* r = (const float*)d_in[2];
  const float* We[4] = {(const float*)d_in[3], (const float*)d_in[4],
                        (const float*)d_in[5], (const float*)d_in[6]};
  const float* Wr[4] = {(const float*)d_in[7], (const float*)d_in[8],
                        (const float*)d_in[9], (const float*)d_in[10]};
  float* out = (float*)d_out;

  char* ws = (char*)d_ws;
  const size_t offB  = 0;                          // entity B images: 4*625*32768
  const size_t offWr = 81920000;                   // Wr images: 4*16*32768
  const size_t offR  = offWr + 2097152;            // rpad
  const size_t offC1 = offR + 4194304;             // 88,211,456
  const size_t C1sz  = 4096ull * 1024ull * 4ull;   // 16,777,216 per ks
  const int KS = (ws_size >= offC1 + 4 * C1sz + 8388608ull) ? 4 : 2;
  const size_t offC2 = offC1 + (size_t)KS * C1sz;

  float* rpad = (float*)(ws + offR);
  float* C1   = (float*)(ws + offC1);
  float* C2   = (float*)(ws + offC2);

  for (int q = 0; q < 4; ++q) {
    convert_b<<<dim3(625), 256, 0, stream>>>(We[q], 20000, ws + offB + (size_t)q * 625 * 32768);
    convert_b<<<dim3(16), 256, 0, stream>>>(Wr[q], 500, ws + offWr + (size_t)q * 16 * 32768);
  }
  pad_r<<<dim3(1, 2048), 128, 0, stream>>>(r, rpad);

  // main: M=4096 ([h;t]), N=1024, K=20000 (625 K-tiles); MT=16 NT=4
  gemm3p<<<dim3(16 * 4 * KS), 512, 131072, stream>>>(
      h, t, 8, 20000L, (const char*)(ws + offB), 625,
      C1, 1024L, 16, 4, KS, KS == 4 ? 1 : 0);
  // r: M=2048, N=1024, K=512 (16 K-tiles); MT=8 NT=4 KS=1
  gemm3p<<<dim3(32), 512, 131072, stream>>>(
      rpad, rpad, 8, 512L, (const char*)(ws + offWr), 16,
      C2, 1024L, 8, 4, 1, 0);

  epilogue_kernel<<<dim3(2048), 256, 0, stream>>>(C1, C2, out, KS);
}